// Round 21
// baseline (77.089 us; speedup 1.0000x reference)
//
#include <hip/hip_runtime.h>

// Problem constants
#define B_ 4
#define E_ 1024
#define S_ 2048
#define H_ 16
#define K_ 1024

#define NCH 32          // scan chunks along S (batch-local)
#define CS  (S_/NCH)    // 64

typedef __bf16 bf16x8 __attribute__((ext_vector_type(8)));
typedef float  f32x4  __attribute__((ext_vector_type(4)));

#define AS1 __attribute__((address_space(1)))
#define AS3 __attribute__((address_space(3)))

__device__ __forceinline__ unsigned short f2bf(float f) {
  unsigned u = __float_as_uint(f);
  u += 0x7fffu + ((u >> 16) & 1u);   // round-to-nearest-even
  return (unsigned short)(u >> 16);
}
__device__ __forceinline__ float bf2f(unsigned short h) {
  return __uint_as_float(((unsigned)h) << 16);
}

// ---------------------------------------------------------------------------
// Merged: x (B,E,S) fp32 -> Xt (B,S,E) bf16 transpose  (blockIdx.z < 4)
//       + weight fp32->bf16 conversion                  (blockIdx.z == 4)
// ---------------------------------------------------------------------------
__global__ __launch_bounds__(256)
void tc_kernel(const float* __restrict__ x, unsigned short* __restrict__ xt,
               const float* __restrict__ inw, const float* __restrict__ outw,
               unsigned short* __restrict__ w1, unsigned short* __restrict__ w2)
{
  if (blockIdx.z == 4) {
    const int per = (E_ * E_) / 4;                 // float4s per matrix
    const int fid = blockIdx.y * 32 + blockIdx.x;  // 0..511
#pragma unroll
    for (int k = 0; k < 4; ++k) {
      int i = fid * 1024 + k * 256 + threadIdx.x;  // 0 .. 2*per-1
      const float4* src = (i < per) ? (const float4*)inw : (const float4*)outw;
      unsigned short* dst = (i < per) ? w1 : w2;
      int j = (i < per) ? i : i - per;
      float4 v = src[j];
      ushort4 o;
      o.x = f2bf(v.x); o.y = f2bf(v.y); o.z = f2bf(v.z); o.w = f2bf(v.w);
      *(ushort4*)(dst + (long)j * 4) = o;
    }
    return;
  }

  __shared__ float t[64][65];
  const int b  = blockIdx.z;
  const int e0 = blockIdx.y * 64;
  const int s0 = blockIdx.x * 64;
  const int tx = threadIdx.x & 63, ty = threadIdx.x >> 6;

  const float* xp = x + ((long)b * E_ + e0) * S_ + s0;
#pragma unroll
  for (int r = 0; r < 16; ++r) {
    int row = r * 4 + ty;                          // e-offset within tile
    t[row][tx] = xp[(long)row * S_ + tx];
  }
  __syncthreads();
  unsigned short* xo = xt + ((long)b * S_ + s0) * E_ + e0;
#pragma unroll
  for (int p = 0; p < 2; ++p) {
    int s = p * 32 + (threadIdx.x >> 3);           // s-offset in tile
    int e = (threadIdx.x & 7) * 8;                 // e-offset in tile
    unsigned short v[8];
#pragma unroll
    for (int j = 0; j < 8; ++j) v[j] = f2bf(t[e + j][s]);
    *(ushort4*)(xo + (long)s * E_ + e)     = make_ushort4(v[0], v[1], v[2], v[3]);
    *(ushort4*)(xo + (long)s * E_ + e + 4) = make_ushort4(v[4], v[5], v[6], v[7]);
  }
}

// ---------------------------------------------------------------------------
// GEMM (R9/R17 champion config): C (8192 x 1024) = A * Wb^T + bias
// 128x128 tile, BK=64, 512 thr = 8 waves (2M x 4N, wave-tile 64x32),
// 64 KB double-buffered XOR-swizzled LDS, stage-early + ONE barrier per
// K-tile (compiler-scheduled waits), T1 XCD tiling, 2 blocks/CU
// (16 waves/CU). Structural sweep R2-R18 brackets this as the optimum.
// VARIANT 0: C = Yt bf16 row-major + fused scan chunk partials -> part.
// VARIANT 1: C = out fp32 written transposed into (B_,E_,S_), via
//            NON-TEMPORAL stores (ext-vector f32x4 — HIP float4 is a
//            struct and rejected by the builtin): out (31 MB, never
//            re-read) otherwise evicts the L2-sized Zt+W2b staging set.
// ---------------------------------------------------------------------------
__device__ __forceinline__ void stage_half(char* lds, const unsigned short* __restrict__ base,
                                           int kt, int ks, int tid) {
  // 512 thr x 16 B = 8 KB = half-tile [128 rows][32 k], swizzled source
  // (T2 both-sides rule: linear LDS dest, inverse-swz global source).
  int row = tid >> 2;                              // 0..127
  int cb  = (tid & 3) << 4;                        // byte col in 64B half-row
  int cbs = cb ^ (((row >> 1) & 3) << 4);
  const unsigned short* src = base + (long)row * K_ + kt + ks * 32 + (cbs >> 1);
  __builtin_amdgcn_global_load_lds((const AS1 void*)src,
      (AS3 void*)(lds + ks * 8192 + tid * 16), 16, 0, 0);
}

__device__ __forceinline__ void stage_tile(char* buf, const unsigned short* __restrict__ Ab,
                                           const unsigned short* __restrict__ Bb,
                                           int kt, int tid) {
  stage_half(buf,         Ab, kt, 0, tid);
  stage_half(buf,         Ab, kt, 1, tid);
  stage_half(buf + 16384, Bb, kt, 0, tid);
  stage_half(buf + 16384, Bb, kt, 1, tid);
}

template<int VARIANT>
__global__ __launch_bounds__(512, 4)
void gemm_hw(const unsigned short* __restrict__ A, const unsigned short* __restrict__ Bw,
             void* __restrict__ Cout, const float* __restrict__ bias,
             const float* __restrict__ mixw, float* __restrict__ part)
{
  __shared__ char smem[65536];                     // 2 x {As[2][128][32], Bs[2][128][32]}

  const int tid  = threadIdx.x;
  const int lane = tid & 63, wid = tid >> 6;
  const int wm = wid >> 2, wn = wid & 3;           // 2M x 4N waves, 64x32 each
  const int lr = lane & 15, lg = lane >> 4;

  // T1: grid 512 = 8 XCD x 64; XCD x owns tm in {8x..8x+7} x all 8 tn.
  const int bid = blockIdx.x;
  const int xcd = bid & 7;
  const int j   = bid >> 3;                        // 0..63
  const int tm  = (xcd << 3) | (j & 7);            // 0..63
  const int tn  = j >> 3;                          // 0..7

  const unsigned short* Ab = A  + (long)tm * 128 * K_;
  const unsigned short* Bb = Bw + (long)tn * 128 * K_;

  f32x4 acc[4][2] = {};

  // Prologue: stage tile 0 into buf0, full drain (compiler vmcnt(0)+barrier).
  stage_tile(smem, Ab, Bb, 0, tid);
  __syncthreads();

  for (int t = 0; t < 16; ++t) {
    char* cur = smem + (t & 1) * 32768;
    char* nxt = smem + ((t + 1) & 1) * 32768;
    if (t + 1 < 16) stage_tile(nxt, Ab, Bb, (t + 1) * 64, tid);  // issue early

#pragma unroll
    for (int ks = 0; ks < 2; ++ks) {
      bf16x8 af[4], bfv[2];
#pragma unroll
      for (int mf = 0; mf < 4; ++mf) {
        int row = wm * 64 + mf * 16 + lr;
        int cb  = (lg * 16) ^ (((row >> 1) & 3) << 4);
        af[mf] = *(const bf16x8*)(cur + ks * 8192 + row * 64 + cb);
      }
#pragma unroll
      for (int nf = 0; nf < 2; ++nf) {
        int row = wn * 32 + nf * 16 + lr;
        int cb  = (lg * 16) ^ (((row >> 1) & 3) << 4);
        bfv[nf] = *(const bf16x8*)(cur + 16384 + ks * 8192 + row * 64 + cb);
      }
#pragma unroll
      for (int mf = 0; mf < 4; ++mf)
#pragma unroll
        for (int nf = 0; nf < 2; ++nf)
          acc[mf][nf] = __builtin_amdgcn_mfma_f32_16x16x32_bf16(
              af[mf], bfv[nf], acc[mf][nf], 0, 0, 0);
    }
    // One barrier per K-tile: drains next-tile loads (after compute covered
    // their latency) and closes the read phase of cur before it's rewritten.
    __syncthreads();
  }

  // Epilogue. C/D frag: col = lane&15, row = (lane>>4)*4 + j  [m89/m91]
  if constexpr (VARIANT == 0) {
    const int bt = tm >> 4;                        // batch (16 m-tiles/batch)
    const int sb = ((tm & 15) << 7) + wm * 64;     // batch-local s of wave base
    const int ch = ((tm & 15) << 1) + wm;          // 64-row chunk (1 per wave)
#pragma unroll
    for (int nf = 0; nf < 2; ++nf) {
      const int c = tn * 128 + wn * 32 + nf * 16 + lr;
      const float bv = bias[c];
      const int h = c >> 6;
      float sm = 0.f;
#pragma unroll
      for (int mf = 0; mf < 4; ++mf) {
#pragma unroll
        for (int jj = 0; jj < 4; ++jj) {
          const int sl = sb + mf * 16 + lg * 4 + jj;
          float v = acc[mf][nf][jj] + bv;
          ((unsigned short*)Cout)[((long)bt * S_ + sl) * E_ + c] = f2bf(v);
          sm += (h < 8) ? v : v * mixw[h * S_ + sl];
        }
      }
      sm += __shfl_xor(sm, 16, 64);
      sm += __shfl_xor(sm, 32, 64);
      if (lg == 0) part[((long)bt * NCH + ch) * E_ + c] = sm;
    }
  } else {
#pragma unroll
    for (int nf = 0; nf < 2; ++nf) {
      const int c = tn * 128 + wn * 32 + nf * 16 + lr;
      const float bv = bias[c];
#pragma unroll
      for (int mf = 0; mf < 4; ++mf) {
        const int r0 = tm * 128 + wm * 64 + mf * 16 + lg * 4;
        const int s = r0 & (S_ - 1);
        const int b = r0 >> 11;
        f32x4 v = acc[mf][nf] + bv;                // ext-vector broadcast add
        // Non-temporal: out stream never re-read; keep Zt/W2b resident in L2.
        __builtin_nontemporal_store(v,
            (f32x4*)((float*)Cout + ((long)b * E_ + c) * S_ + s));
      }
    }
  }
}

// ---------------------------------------------------------------------------
// scan_final: causal prefix combine using chunk partials from GEMM1 epilogue.
//   h < 8 : z[s,c] = mix_w[h,s] * (prior-chunk sums + intra-chunk cumsum)
//   h >= 8: z[s,c] = (prior weighted sums + intra-chunk weighted cumsum)
// XCD-affinity decode: Yt rows for (b, ch) were written by GEMM1 on
// xcd = 2b + (ch>>4) (T1 map, tm>>3). Decode bid so this block lands on
// that same XCD: its Yt reads and Zt writes stay in the local L2, and
// GEMM2 (same T1 map) then reads Zt L2-warm. Bijective over 512 blocks.
// ---------------------------------------------------------------------------
__global__ __launch_bounds__(256)
void scan_final(const unsigned short* __restrict__ yt, const float* __restrict__ mixw,
                const float* __restrict__ mixb, const float* __restrict__ part,
                unsigned short* __restrict__ zt)
{
  const int bid = blockIdx.x;                      // 0..511, xcd = bid&7
  const int xcd = bid & 7;
  const int b   = xcd >> 1;                        // batch
  const int j   = bid >> 3;                        // 0..63
  const int ch  = ((xcd & 1) << 4) | (j & 15);     // chunk 0..31
  const int c   = (j >> 4) * 256 + threadIdx.x;    // channel 0..1023
  const int h   = c >> 6;

  float acc = 0.f;
  for (int p = 0; p < ch; ++p) acc += part[((long)b * NCH + p) * E_ + c];
  const unsigned short* yp = yt + ((long)b * S_ + ch * CS) * E_ + c;
  unsigned short*       zp = zt + ((long)b * S_ + ch * CS) * E_ + c;
  const float* mw = mixw + (long)h * S_ + ch * CS;
  const float* mb = mixb + (long)h * S_ + ch * CS;
  if (h < 8) {
    for (int s = 0; s < CS; ++s) {
      acc += bf2f(yp[(long)s * E_]);
      zp[(long)s * E_] = f2bf(fmaf(acc, mw[s], mb[s]));
    }
  } else {
    for (int s = 0; s < CS; ++s) {
      acc += bf2f(yp[(long)s * E_]) * mw[s];
      zp[(long)s * E_] = f2bf(acc + mb[s]);
    }
  }
}

// ---------------------------------------------------------------------------
extern "C" void kernel_launch(void* const* d_in, const int* in_sizes, int n_in,
                              void* d_out, int out_size, void* d_ws, size_t ws_size,
                              hipStream_t stream)
{
  (void)in_sizes; (void)n_in; (void)out_size; (void)ws_size;
  const float* x     = (const float*)d_in[0];
  const float* in_w  = (const float*)d_in[1];
  const float* in_b  = (const float*)d_in[2];
  const float* out_w = (const float*)d_in[3];
  const float* out_b = (const float*)d_in[4];
  const float* mix_w = (const float*)d_in[5];
  const float* mix_b = (const float*)d_in[6];

  char* ws = (char*)d_ws;
  unsigned short* Xt  = (unsigned short*)(ws);                            // 16 MB (reused as Zt)
  unsigned short* Yt  = (unsigned short*)(ws + (size_t)16 * 1024 * 1024); // 16 MB
  unsigned short* W1b = (unsigned short*)(ws + (size_t)32 * 1024 * 1024); // 2 MB
  unsigned short* W2b = (unsigned short*)(ws + (size_t)34 * 1024 * 1024); // 2 MB
  float*          part = (float*)(ws + (size_t)36 * 1024 * 1024);         // 512 KB
  unsigned short* Zt  = Xt;

  // transpose+convert (z<4: transpose batch z; z==4: weight convert)
  tc_kernel<<<dim3(S_ / 64, E_ / 64, 5), 256, 0, stream>>>(x, Xt, in_w, out_w, W1b, W2b);

  // in_proj + fused scan partials: Yt = Xt * W1b^T + in_b ; part = chunk sums
  gemm_hw<0><<<dim3(512), 512, 0, stream>>>(Xt, W1b, Yt, in_b, mix_w, part);

  // causal mix combine (XCD-affine decode, flat grid 512)
  scan_final<<<dim3(512), 256, 0, stream>>>(Yt, mix_w, mix_b, part, Zt);

  // out_proj: out(b,e,s) = transposed-write of Zt * W2b^T + out_b (nt stores)
  gemm_hw<1><<<dim3(512), 512, 0, stream>>>(Zt, W2b, d_out, out_b, nullptr, nullptr);
}

// Round 22
// 75.652 us; speedup vs baseline: 1.0190x; 1.0190x over previous
//
#include <hip/hip_runtime.h>

// Problem constants
#define B_ 4
#define E_ 1024
#define S_ 2048
#define H_ 16
#define K_ 1024

#define NCH 32          // scan chunks along S (batch-local)
#define CS  (S_/NCH)    // 64

typedef __bf16 bf16x8 __attribute__((ext_vector_type(8)));
typedef float  f32x4  __attribute__((ext_vector_type(4)));

#define AS1 __attribute__((address_space(1)))
#define AS3 __attribute__((address_space(3)))

__device__ __forceinline__ unsigned short f2bf(float f) {
  unsigned u = __float_as_uint(f);
  u += 0x7fffu + ((u >> 16) & 1u);   // round-to-nearest-even
  return (unsigned short)(u >> 16);
}
__device__ __forceinline__ float bf2f(unsigned short h) {
  return __uint_as_float(((unsigned)h) << 16);
}

// ---------------------------------------------------------------------------
// Merged: x (B,E,S) fp32 -> Xt (B,S,E) bf16 transpose  (blockIdx.z < 4)
//       + weight fp32->bf16 conversion                  (blockIdx.z == 4)
// ---------------------------------------------------------------------------
__global__ __launch_bounds__(256)
void tc_kernel(const float* __restrict__ x, unsigned short* __restrict__ xt,
               const float* __restrict__ inw, const float* __restrict__ outw,
               unsigned short* __restrict__ w1, unsigned short* __restrict__ w2)
{
  if (blockIdx.z == 4) {
    const int per = (E_ * E_) / 4;                 // float4s per matrix
    const int fid = blockIdx.y * 32 + blockIdx.x;  // 0..511
#pragma unroll
    for (int k = 0; k < 4; ++k) {
      int i = fid * 1024 + k * 256 + threadIdx.x;  // 0 .. 2*per-1
      const float4* src = (i < per) ? (const float4*)inw : (const float4*)outw;
      unsigned short* dst = (i < per) ? w1 : w2;
      int j = (i < per) ? i : i - per;
      float4 v = src[j];
      ushort4 o;
      o.x = f2bf(v.x); o.y = f2bf(v.y); o.z = f2bf(v.z); o.w = f2bf(v.w);
      *(ushort4*)(dst + (long)j * 4) = o;
    }
    return;
  }

  __shared__ float t[64][65];
  const int b  = blockIdx.z;
  const int e0 = blockIdx.y * 64;
  const int s0 = blockIdx.x * 64;
  const int tx = threadIdx.x & 63, ty = threadIdx.x >> 6;

  const float* xp = x + ((long)b * E_ + e0) * S_ + s0;
#pragma unroll
  for (int r = 0; r < 16; ++r) {
    int row = r * 4 + ty;                          // e-offset within tile
    t[row][tx] = xp[(long)row * S_ + tx];
  }
  __syncthreads();
  unsigned short* xo = xt + ((long)b * S_ + s0) * E_ + e0;
#pragma unroll
  for (int p = 0; p < 2; ++p) {
    int s = p * 32 + (threadIdx.x >> 3);           // s-offset in tile
    int e = (threadIdx.x & 7) * 8;                 // e-offset in tile
    unsigned short v[8];
#pragma unroll
    for (int j = 0; j < 8; ++j) v[j] = f2bf(t[e + j][s]);
    *(ushort4*)(xo + (long)s * E_ + e)     = make_ushort4(v[0], v[1], v[2], v[3]);
    *(ushort4*)(xo + (long)s * E_ + e + 4) = make_ushort4(v[4], v[5], v[6], v[7]);
  }
}

// ---------------------------------------------------------------------------
// GEMM (R9/R17 champion config): C (8192 x 1024) = A * Wb^T + bias
// 128x128 tile, BK=64, 512 thr = 8 waves (2M x 4N, wave-tile 64x32),
// 64 KB double-buffered XOR-swizzled LDS, stage-early + ONE barrier per
// K-tile (compiler-scheduled waits), T1 XCD tiling, 2 blocks/CU
// (16 waves/CU). Structural sweep R2-R21 (12 variants incl. NT stores)
// brackets this as the optimum: every deviation measured equal or worse.
// VARIANT 0: C = Yt bf16 row-major + fused scan chunk partials -> part.
// VARIANT 1: C = out fp32 written transposed into (B_,E_,S_).
// ---------------------------------------------------------------------------
__device__ __forceinline__ void stage_half(char* lds, const unsigned short* __restrict__ base,
                                           int kt, int ks, int tid) {
  // 512 thr x 16 B = 8 KB = half-tile [128 rows][32 k], swizzled source
  // (T2 both-sides rule: linear LDS dest, inverse-swz global source).
  int row = tid >> 2;                              // 0..127
  int cb  = (tid & 3) << 4;                        // byte col in 64B half-row
  int cbs = cb ^ (((row >> 1) & 3) << 4);
  const unsigned short* src = base + (long)row * K_ + kt + ks * 32 + (cbs >> 1);
  __builtin_amdgcn_global_load_lds((const AS1 void*)src,
      (AS3 void*)(lds + ks * 8192 + tid * 16), 16, 0, 0);
}

__device__ __forceinline__ void stage_tile(char* buf, const unsigned short* __restrict__ Ab,
                                           const unsigned short* __restrict__ Bb,
                                           int kt, int tid) {
  stage_half(buf,         Ab, kt, 0, tid);
  stage_half(buf,         Ab, kt, 1, tid);
  stage_half(buf + 16384, Bb, kt, 0, tid);
  stage_half(buf + 16384, Bb, kt, 1, tid);
}

template<int VARIANT>
__global__ __launch_bounds__(512, 4)
void gemm_hw(const unsigned short* __restrict__ A, const unsigned short* __restrict__ Bw,
             void* __restrict__ Cout, const float* __restrict__ bias,
             const float* __restrict__ mixw, float* __restrict__ part)
{
  __shared__ char smem[65536];                     // 2 x {As[2][128][32], Bs[2][128][32]}

  const int tid  = threadIdx.x;
  const int lane = tid & 63, wid = tid >> 6;
  const int wm = wid >> 2, wn = wid & 3;           // 2M x 4N waves, 64x32 each
  const int lr = lane & 15, lg = lane >> 4;

  // T1: grid 512 = 8 XCD x 64; XCD x owns tm in {8x..8x+7} x all 8 tn.
  const int bid = blockIdx.x;
  const int xcd = bid & 7;
  const int j   = bid >> 3;                        // 0..63
  const int tm  = (xcd << 3) | (j & 7);            // 0..63
  const int tn  = j >> 3;                          // 0..7

  const unsigned short* Ab = A  + (long)tm * 128 * K_;
  const unsigned short* Bb = Bw + (long)tn * 128 * K_;

  f32x4 acc[4][2] = {};

  // Prologue: stage tile 0 into buf0, full drain (compiler vmcnt(0)+barrier).
  stage_tile(smem, Ab, Bb, 0, tid);
  __syncthreads();

  for (int t = 0; t < 16; ++t) {
    char* cur = smem + (t & 1) * 32768;
    char* nxt = smem + ((t + 1) & 1) * 32768;
    if (t + 1 < 16) stage_tile(nxt, Ab, Bb, (t + 1) * 64, tid);  // issue early

#pragma unroll
    for (int ks = 0; ks < 2; ++ks) {
      bf16x8 af[4], bfv[2];
#pragma unroll
      for (int mf = 0; mf < 4; ++mf) {
        int row = wm * 64 + mf * 16 + lr;
        int cb  = (lg * 16) ^ (((row >> 1) & 3) << 4);
        af[mf] = *(const bf16x8*)(cur + ks * 8192 + row * 64 + cb);
      }
#pragma unroll
      for (int nf = 0; nf < 2; ++nf) {
        int row = wn * 32 + nf * 16 + lr;
        int cb  = (lg * 16) ^ (((row >> 1) & 3) << 4);
        bfv[nf] = *(const bf16x8*)(cur + 16384 + ks * 8192 + row * 64 + cb);
      }
#pragma unroll
      for (int mf = 0; mf < 4; ++mf)
#pragma unroll
        for (int nf = 0; nf < 2; ++nf)
          acc[mf][nf] = __builtin_amdgcn_mfma_f32_16x16x32_bf16(
              af[mf], bfv[nf], acc[mf][nf], 0, 0, 0);
    }
    // One barrier per K-tile: drains next-tile loads (after compute covered
    // their latency) and closes the read phase of cur before it's rewritten.
    __syncthreads();
  }

  // Epilogue. C/D frag: col = lane&15, row = (lane>>4)*4 + j  [m89/m91]
  if constexpr (VARIANT == 0) {
    const int bt = tm >> 4;                        // batch (16 m-tiles/batch)
    const int sb = ((tm & 15) << 7) + wm * 64;     // batch-local s of wave base
    const int ch = ((tm & 15) << 1) + wm;          // 64-row chunk (1 per wave)
#pragma unroll
    for (int nf = 0; nf < 2; ++nf) {
      const int c = tn * 128 + wn * 32 + nf * 16 + lr;
      const float bv = bias[c];
      const int h = c >> 6;
      float sm = 0.f;
#pragma unroll
      for (int mf = 0; mf < 4; ++mf) {
#pragma unroll
        for (int jj = 0; jj < 4; ++jj) {
          const int sl = sb + mf * 16 + lg * 4 + jj;
          float v = acc[mf][nf][jj] + bv;
          ((unsigned short*)Cout)[((long)bt * S_ + sl) * E_ + c] = f2bf(v);
          sm += (h < 8) ? v : v * mixw[h * S_ + sl];
        }
      }
      sm += __shfl_xor(sm, 16, 64);
      sm += __shfl_xor(sm, 32, 64);
      if (lg == 0) part[((long)bt * NCH + ch) * E_ + c] = sm;
    }
  } else {
#pragma unroll
    for (int nf = 0; nf < 2; ++nf) {
      const int c = tn * 128 + wn * 32 + nf * 16 + lr;
      const float bv = bias[c];
#pragma unroll
      for (int mf = 0; mf < 4; ++mf) {
        const int r0 = tm * 128 + wm * 64 + mf * 16 + lg * 4;
        const int s = r0 & (S_ - 1);
        const int b = r0 >> 11;
        float4 v;
        v.x = acc[mf][nf][0] + bv; v.y = acc[mf][nf][1] + bv;
        v.z = acc[mf][nf][2] + bv; v.w = acc[mf][nf][3] + bv;
        *(float4*)((float*)Cout + ((long)b * E_ + c) * S_ + s) = v;
      }
    }
  }
}

// ---------------------------------------------------------------------------
// scan_final: causal prefix combine using chunk partials from GEMM1 epilogue.
//   h < 8 : z[s,c] = mix_w[h,s] * (prior-chunk sums + intra-chunk cumsum)
//   h >= 8: z[s,c] = (prior weighted sums + intra-chunk weighted cumsum)
// XCD-affinity decode: Yt rows for (b, ch) were written by GEMM1 on
// xcd = 2b + (ch>>4) (T1 map, tm>>3). Decode bid so this block lands on
// that same XCD: its Yt reads and Zt writes stay in the local L2, and
// GEMM2 (same T1 map) then reads Zt L2-warm. Bijective over 512 blocks.
// ---------------------------------------------------------------------------
__global__ __launch_bounds__(256)
void scan_final(const unsigned short* __restrict__ yt, const float* __restrict__ mixw,
                const float* __restrict__ mixb, const float* __restrict__ part,
                unsigned short* __restrict__ zt)
{
  const int bid = blockIdx.x;                      // 0..511, xcd = bid&7
  const int xcd = bid & 7;
  const int b   = xcd >> 1;                        // batch
  const int j   = bid >> 3;                        // 0..63
  const int ch  = ((xcd & 1) << 4) | (j & 15);     // chunk 0..31
  const int c   = (j >> 4) * 256 + threadIdx.x;    // channel 0..1023
  const int h   = c >> 6;

  float acc = 0.f;
  for (int p = 0; p < ch; ++p) acc += part[((long)b * NCH + p) * E_ + c];
  const unsigned short* yp = yt + ((long)b * S_ + ch * CS) * E_ + c;
  unsigned short*       zp = zt + ((long)b * S_ + ch * CS) * E_ + c;
  const float* mw = mixw + (long)h * S_ + ch * CS;
  const float* mb = mixb + (long)h * S_ + ch * CS;
  if (h < 8) {
    for (int s = 0; s < CS; ++s) {
      acc += bf2f(yp[(long)s * E_]);
      zp[(long)s * E_] = f2bf(fmaf(acc, mw[s], mb[s]));
    }
  } else {
    for (int s = 0; s < CS; ++s) {
      acc += bf2f(yp[(long)s * E_]) * mw[s];
      zp[(long)s * E_] = f2bf(acc + mb[s]);
    }
  }
}

// ---------------------------------------------------------------------------
extern "C" void kernel_launch(void* const* d_in, const int* in_sizes, int n_in,
                              void* d_out, int out_size, void* d_ws, size_t ws_size,
                              hipStream_t stream)
{
  (void)in_sizes; (void)n_in; (void)out_size; (void)ws_size;
  const float* x     = (const float*)d_in[0];
  const float* in_w  = (const float*)d_in[1];
  const float* in_b  = (const float*)d_in[2];
  const float* out_w = (const float*)d_in[3];
  const float* out_b = (const float*)d_in[4];
  const float* mix_w = (const float*)d_in[5];
  const float* mix_b = (const float*)d_in[6];

  char* ws = (char*)d_ws;
  unsigned short* Xt  = (unsigned short*)(ws);                            // 16 MB (reused as Zt)
  unsigned short* Yt  = (unsigned short*)(ws + (size_t)16 * 1024 * 1024); // 16 MB
  unsigned short* W1b = (unsigned short*)(ws + (size_t)32 * 1024 * 1024); // 2 MB
  unsigned short* W2b = (unsigned short*)(ws + (size_t)34 * 1024 * 1024); // 2 MB
  float*          part = (float*)(ws + (size_t)36 * 1024 * 1024);         // 512 KB
  unsigned short* Zt  = Xt;

  // transpose+convert (z<4: transpose batch z; z==4: weight convert)
  tc_kernel<<<dim3(S_ / 64, E_ / 64, 5), 256, 0, stream>>>(x, Xt, in_w, out_w, W1b, W2b);

  // in_proj + fused scan partials: Yt = Xt * W1b^T + in_b ; part = chunk sums
  gemm_hw<0><<<dim3(512), 512, 0, stream>>>(Xt, W1b, Yt, in_b, mix_w, part);

  // causal mix combine (XCD-affine decode, flat grid 512)
  scan_final<<<dim3(512), 256, 0, stream>>>(Yt, mix_w, mix_b, part, Zt);

  // out_proj: out(b,e,s) = transposed-write of Zt * W2b^T + out_b
  gemm_hw<1><<<dim3(512), 512, 0, stream>>>(Zt, W2b, d_out, out_b, nullptr, nullptr);
}